// Round 3
// baseline (262.273 us; speedup 1.0000x reference)
//
#include <hip/hip_runtime.h>
#include <hip/hip_bf16.h>

typedef const float* fp32p;

// ---------------- workspace layout (bytes) ----------------
// h1 (reused as h3): 64*128*128*16 f32 = 67,108,864 B   @ 0
// h2: 64*64*64*4 f32 = 4,194,304 B                      @ 67,108,864
// di: 64*64*64*4 f32 = 4,194,304 B                      @ 71,303,168
// bn: double[128]                                       @ 75,497,472
//     [0:16) s1 [16:32) q1 [32:36) s2 [36:40) q2 [40:56) s3 [56:72) q3
// redE: double[256]  @ bn + 128 doubles
// redH: double[4096] @ bn + 384 doubles
// total = 75,533,312 B

__device__ __forceinline__ double block_sum_all_d(double v, double* sm){
  #pragma unroll
  for (int m=1;m<64;m<<=1) v += __shfl_xor(v, m, 64);
  int lane = threadIdx.x & 63, wid = threadIdx.x >> 6;
  if (lane==0) sm[wid] = v;
  __syncthreads();
  return sm[0]+sm[1]+sm[2]+sm[3];
}

__global__ __launch_bounds__(128) void k_init(double* __restrict__ bn){
  bn[threadIdx.x] = 0.0;
}

// ---------------- K1: conv1 1->16, k4 s2 p1, x[64,1,256,256] -> h1 NHWC f32 [64,128,128,16]
__global__ __launch_bounds__(256) void k_conv1(fp32p x, fp32p w1, fp32p b1, float* __restrict__ h1){
  __shared__ float sw[256];   // [ky][kx][co]
  __shared__ float sb[16];
  int tid = threadIdx.x;
  {
    int co = tid & 15, kx = (tid>>4)&3, ky = tid>>6;
    sw[tid] = w1[co*16 + ky*4 + kx];
    if (tid < 16) sb[tid] = b1[tid];
  }
  __syncthreads();
  int gid = blockIdx.x*256 + tid;           // 64*128*128 threads
  int ox = gid & 127, oy = (gid>>7)&127, n = gid>>14;
  float acc[16];
  #pragma unroll
  for (int c=0;c<16;c++) acc[c] = sb[c];
  #pragma unroll
  for (int ky=0; ky<4; ky++){
    int iy = oy*2 - 1 + ky;
    bool rok = (unsigned)iy < 256u;
    #pragma unroll
    for (int kx=0; kx<4; kx++){
      int ix = ox*2 - 1 + kx;
      float v = (rok && ((unsigned)ix < 256u)) ? x[n*65536 + iy*256 + ix] : 0.f;
      const float* wp = &sw[(ky*4+kx)*16];
      #pragma unroll
      for (int c=0;c<16;c++) acc[c] = fmaf(v, wp[c], acc[c]);
    }
  }
  float* o = &h1[(unsigned)gid*16u];
  #pragma unroll
  for (int q=0;q<4;q++)
    *(float4*)&o[q*4] = make_float4(acc[q*4],acc[q*4+1],acc[q*4+2],acc[q*4+3]);
}

// ---------------- stats: per-channel sum & sumsq (fp64 accumulation) of NHWC f32 tensor
template<int C>
__global__ __launch_bounds__(256) void k_statsd(const float* __restrict__ h, int n4,
                                                double* __restrict__ bnp){
  constexpr int P = C/4;                    // float4-groups per pixel
  __shared__ double smem[4][P][8];
  int tid = threadIdx.x;
  int gid = blockIdx.x*256 + tid;
  int stride = gridDim.x*256;               // multiple of P -> group stable per lane
  double a[8];
  #pragma unroll
  for (int k=0;k<8;k++) a[k]=0.0;
  const float4* h4 = (const float4*)h;
  for (int i = gid; i < n4; i += stride){
    float4 v = h4[i];
    double dx=v.x, dy=v.y, dz=v.z, dw=v.w;
    a[0]+=dx; a[1]+=dy; a[2]+=dz; a[3]+=dw;
    a[4]=fma(dx,dx,a[4]); a[5]=fma(dy,dy,a[5]);
    a[6]=fma(dz,dz,a[6]); a[7]=fma(dw,dw,a[7]);
  }
  #pragma unroll
  for (int m=P;m<64;m<<=1){
    #pragma unroll
    for (int k=0;k<8;k++) a[k] += __shfl_xor(a[k], m, 64);
  }
  int lane = tid & 63, wid = tid >> 6;
  if (lane < P){
    #pragma unroll
    for (int k=0;k<8;k++) smem[wid][lane][k] = a[k];
  }
  __syncthreads();
  if (tid < P*8){
    int g = tid >> 3, k = tid & 7;
    double v = smem[0][g][k]+smem[1][g][k]+smem[2][g][k]+smem[3][g][k];
    atomicAdd(&bnp[(k>>2)*C + g*4 + (k&3)], v);   // [0:C) sums, [C:2C) sumsq
  }
}

// ---------------- K3: BN1+ReLU fused read, conv2 16->4, k4 s2 p1 -> h2 f32 [64,64,64,4]
__global__ __launch_bounds__(256) void k_conv2(const float* __restrict__ h1, fp32p w2, fp32p b2,
    fp32p g1, fp32p be1, const double* __restrict__ bn, float* __restrict__ h2){
  __shared__ float sw[1024];   // [ky][kx][ci16][co4]
  __shared__ float sb[4];
  int tid = threadIdx.x;
  for (int j=tid;j<1024;j+=256){
    int co=j&3, ci=(j>>2)&15, kx=(j>>6)&3, ky=j>>8;
    sw[j] = w2[((co*16+ci)*4+ky)*4+kx];
  }
  if (tid<4) sb[tid]=b2[tid];
  __syncthreads();
  float sc[16], sh[16];
  const double invM = 1.0/1048576.0;
  #pragma unroll
  for (int c=0;c<16;c++){
    double m = bn[c]*invM;
    double var = fma(-m,m, bn[16+c]*invM);
    double s = (double)g1[c] / sqrt(var + 1e-5);
    sc[c]=(float)s; sh[c]=(float)((double)be1[c] - m*s);
  }
  int gid = blockIdx.x*256+tid;             // 64*64*64 threads
  int ox = gid&63, oy=(gid>>6)&63, n=gid>>12;
  float a0=sb[0],a1=sb[1],a2=sb[2],a3=sb[3];
  #pragma unroll
  for (int ky=0;ky<4;ky++){
    int iy = oy*2-1+ky;
    if ((unsigned)iy >= 128u) continue;
    #pragma unroll
    for (int kx=0;kx<4;kx++){
      int ix = ox*2-1+kx;
      if ((unsigned)ix >= 128u) continue;
      const float4* hp = (const float4*)&h1[((n*128+iy)*128+ix)*16];
      const float* wp = &sw[(ky*4+kx)*64];
      #pragma unroll
      for (int c4=0;c4<4;c4++){
        float4 hv = hp[c4];
        float vv[4]={hv.x,hv.y,hv.z,hv.w};
        #pragma unroll
        for (int u=0;u<4;u++){
          int ci=c4*4+u;
          float v = fmaxf(fmaf(vv[u], sc[ci], sh[ci]), 0.f);
          const float* w4 = &wp[ci*4];
          a0 = fmaf(v,w4[0],a0); a1 = fmaf(v,w4[1],a1);
          a2 = fmaf(v,w4[2],a2); a3 = fmaf(v,w4[3],a3);
        }
      }
    }
  }
  *(float4*)&h2[(unsigned)gid*4u] = make_float4(a0,a1,a2,a3);
}

// ---------------- K5: BN2+ReLU -> pre 1x1 -> VQ argmin (fp64) -> loss partial -> post 1x1 -> di
__global__ __launch_bounds__(256) void k_vq(const float* __restrict__ h2,
    fp32p g2, fp32p be2, const double* __restrict__ bn,
    fp32p wpre, fp32p bpre, fp32p emb, fp32p wpost, fp32p bpost,
    float* __restrict__ di, double* __restrict__ redE){
  __shared__ double se[128];
  __shared__ double sm[4];
  int tid = threadIdx.x;
  if (tid < 128) se[tid] = (double)emb[tid];
  __syncthreads();
  double sc[4], sh[4];
  const double invM = 1.0/262144.0;
  #pragma unroll
  for (int c=0;c<4;c++){
    double m = bn[32+c]*invM;
    double var = fma(-m,m, bn[36+c]*invM);
    double s = (double)g2[c] / sqrt(var + 1e-5);
    sc[c]=s; sh[c]=(double)be2[c] - m*s;
  }
  double wa0=wpre[0], wa1=wpre[1], wa2=wpre[2], wa3=wpre[3];
  double wb0=wpre[4], wb1=wpre[5], wb2=wpre[6], wb3=wpre[7];
  double bp0=bpre[0], bp1=bpre[1];
  double p00=wpost[0], p01=wpost[1];
  double p10=wpost[2], p11=wpost[3];
  double p20=wpost[4], p21=wpost[5];
  double p30=wpost[6], p31=wpost[7];
  double bq0=bpost[0], bq1=bpost[1], bq2=bpost[2], bq3=bpost[3];
  int gid = blockIdx.x*256 + tid;           // 65536 threads, 4 pixels each
  double lsum = 0.0;
  #pragma unroll
  for (int it=0; it<4; it++){
    int p = gid + it*65536;
    float4 hv = *(const float4*)&h2[(unsigned)p*4u];
    double h0 = fmax(fma((double)hv.x, sc[0], sh[0]), 0.0);
    double h1v = fmax(fma((double)hv.y, sc[1], sh[1]), 0.0);
    double h2v = fmax(fma((double)hv.z, sc[2], sh[2]), 0.0);
    double h3v = fmax(fma((double)hv.w, sc[3], sh[3]), 0.0);
    double z0 = bp0 + wa0*h0 + wa1*h1v + wa2*h2v + wa3*h3v;
    double z1 = bp1 + wb0*h0 + wb1*h1v + wb2*h2v + wb3*h3v;
    double best = 1e300; int bi = 0;
    #pragma unroll
    for (int k=0;k<64;k++){
      double d0 = z0 - se[2*k], d1 = z1 - se[2*k+1];
      double d = fma(d0,d0, d1*d1);
      if (d < best){ best = d; bi = k; }    // first-min tie rule == argmin
    }
    double qv0 = se[2*bi], qv1 = se[2*bi+1];
    double e0 = qv0-z0, e1 = qv1-z1;
    lsum += fma(e0,e0, e1*e1);
    float4 o;
    o.x = (float)(fma(p00,qv0, fma(p01,qv1, bq0)));
    o.y = (float)(fma(p10,qv0, fma(p11,qv1, bq1)));
    o.z = (float)(fma(p20,qv0, fma(p21,qv1, bq2)));
    o.w = (float)(fma(p30,qv0, fma(p31,qv1, bq3)));
    *(float4*)&di[(unsigned)p*4u] = o;
  }
  double tot = block_sum_all_d(lsum, sm);
  if (tid==0) redE[blockIdx.x] = tot;
}

// ---------------- K6: convT1 4->16, k4 s2 p1: di -> h3 NHWC f32 [64,128,128,16]
__global__ __launch_bounds__(256) void k_convt1(const float* __restrict__ di, fp32p wd1, fp32p bd1,
                                                float* __restrict__ h3){
  __shared__ float sw[1024];  // [ky][kx][ci4][co16]
  __shared__ float sb[16];
  int tid = threadIdx.x;
  for (int j=tid; j<1024; j+=256){
    int co = j & 15, ci = (j>>4)&3, kx = (j>>6)&3, ky = j>>8;
    sw[j] = wd1[((ci*16+co)*4+ky)*4+kx];   // wd1 [in4][out16][4][4]
  }
  if (tid<16) sb[tid] = bd1[tid];
  __syncthreads();
  int gid = blockIdx.x*256 + tid;          // 64*128*128 threads
  int ox = gid & 127, oy = (gid>>7)&127, n = gid>>14;
  float acc[16];
  #pragma unroll
  for (int c=0;c<16;c++) acc[c]=sb[c];
  int py=(oy+1)&1, px=(ox+1)&1;
  #pragma unroll
  for (int j=0;j<2;j++){
    int ky = py + 2*j;
    int iy = (oy+1-ky) >> 1;
    if ((unsigned)iy >= 64u) continue;
    #pragma unroll
    for (int i=0;i<2;i++){
      int kx = px + 2*i;
      int ix = (ox+1-kx) >> 1;
      if ((unsigned)ix >= 64u) continue;
      float4 dv = *(const float4*)&di[((n*64+iy)*64+ix)*4];
      const float* wb = &sw[((ky*4+kx)*4)*16];
      float vv[4] = {dv.x, dv.y, dv.z, dv.w};
      #pragma unroll
      for (int ci=0;ci<4;ci++){
        #pragma unroll
        for (int co=0;co<16;co++)
          acc[co] = fmaf(vv[ci], wb[ci*16+co], acc[co]);
      }
    }
  }
  float* o = &h3[(unsigned)gid*16u];
  #pragma unroll
  for (int q=0;q<4;q++) *(float4*)&o[q*4] = make_float4(acc[q*4],acc[q*4+1],acc[q*4+2],acc[q*4+3]);
}

// ---------------- K8: BN3+ReLU fused, convT2 16->1, tanh -> out f32; recon partials (fp64)
__global__ __launch_bounds__(256) void k_convt2(const float* __restrict__ h3, fp32p wd2, fp32p bd2,
    fp32p g3, fp32p be3, const double* __restrict__ bn,
    fp32p x, float* __restrict__ out, double* __restrict__ redH){
  __shared__ float sw[256];   // [ky][kx][ci16]
  __shared__ double sm[4];
  int tid = threadIdx.x;
  { int ci = tid & 15, kx = (tid>>4)&3, ky = tid>>6;
    sw[tid] = wd2[ci*16 + ky*4 + kx]; }   // wd2 [in16][out1][4][4]
  __syncthreads();
  float sc[16], sh[16];
  const double invM = 1.0/1048576.0;
  #pragma unroll
  for (int c=0;c<16;c++){
    double m = bn[40+c]*invM;
    double var = fma(-m,m, bn[56+c]*invM);
    double s = (double)g3[c] / sqrt(var + 1e-5);
    sc[c]=(float)s; sh[c]=(float)((double)be3[c] - m*s);
  }
  float bias = bd2[0];
  int gid = blockIdx.x*256 + tid;           // 1,048,576 threads, 4 pixels each
  double rsum = 0.0;
  #pragma unroll
  for (int it=0; it<4; it++){
    int p = gid + it*1048576;
    int ox = p & 255, oy = (p>>8)&255, n = p>>16;
    int py = (oy+1)&1, px = (ox+1)&1;
    float acc = bias;
    #pragma unroll
    for (int j=0;j<2;j++){
      int ky = py + 2*j;
      int iy = (oy + 1 - ky) >> 1;
      if ((unsigned)iy >= 128u) continue;
      #pragma unroll
      for (int i=0;i<2;i++){
        int kx = px + 2*i;
        int ix = (ox + 1 - kx) >> 1;
        if ((unsigned)ix >= 128u) continue;
        const float4* hp = (const float4*)&h3[((n*128+iy)*128+ix)*16];
        const float* w16 = &sw[(ky*4+kx)*16];
        #pragma unroll
        for (int c4=0;c4<4;c4++){
          float4 hv = hp[c4];
          float v;
          v = fmaxf(fmaf(hv.x, sc[c4*4+0], sh[c4*4+0]), 0.f); acc = fmaf(v, w16[c4*4+0], acc);
          v = fmaxf(fmaf(hv.y, sc[c4*4+1], sh[c4*4+1]), 0.f); acc = fmaf(v, w16[c4*4+1], acc);
          v = fmaxf(fmaf(hv.z, sc[c4*4+2], sh[c4*4+2]), 0.f); acc = fmaf(v, w16[c4*4+2], acc);
          v = fmaxf(fmaf(hv.w, sc[c4*4+3], sh[c4*4+3]), 0.f); acc = fmaf(v, w16[c4*4+3], acc);
        }
      }
    }
    float e = __expf(2.f*acc);
    float t = 1.f - 2.f/(e+1.f);            // tanh
    out[p] = t;
    double dd = (double)x[p] - (double)t;
    rsum = fma(dd,dd,rsum);
  }
  double tot = block_sum_all_d(rsum, sm);
  if (tid==0) redH[blockIdx.x] = tot;
}

// ---------------- K9: finalize loss
__global__ __launch_bounds__(256) void k_final(const double* __restrict__ redE, const double* __restrict__ redH,
                                               float* __restrict__ out, int out_size){
  __shared__ double sm[4];
  int tid = threadIdx.x;
  double a = redE[tid];        // exactly 256 entries
  double b = 0.0;
  for (int i=tid;i<4096;i+=256) b += redH[i];
  double ta = block_sum_all_d(a, sm);
  __syncthreads();
  double tb = block_sum_all_d(b, sm);
  if (tid==0){
    double loss = 1.2*ta/524288.0 + tb/4194304.0;  // (1+BETA)*mean((q-z)^2) + recon_mean
    out[out_size-1] = (float)loss;
  }
}

extern "C" void kernel_launch(void* const* d_in, const int* in_sizes, int n_in,
                              void* d_out, int out_size, void* d_ws, size_t ws_size,
                              hipStream_t stream) {
  (void)ws_size;
  // Inputs in setup_inputs() dict order; defensive remap if layout is alphabetical.
  int I[20];
  for (int i=0;i<20;i++) I[i]=i;
  if (n_in >= 20 && in_sizes[0] != 4194304 && in_sizes[19] == 4194304){
    static const int remap[20] = {19,13,0,10,4,14,1,11,5,18,8,9,17,7,15,2,12,6,16,3};
    for (int i=0;i<20;i++) I[i]=remap[i];
  }
  fp32p x    = (fp32p)d_in[I[0]];
  fp32p w1   = (fp32p)d_in[I[1]],  b1 = (fp32p)d_in[I[2]],  g1 = (fp32p)d_in[I[3]],  be1 = (fp32p)d_in[I[4]];
  fp32p w2   = (fp32p)d_in[I[5]],  b2 = (fp32p)d_in[I[6]],  g2 = (fp32p)d_in[I[7]],  be2 = (fp32p)d_in[I[8]];
  fp32p wpre = (fp32p)d_in[I[9]],  bpre = (fp32p)d_in[I[10]], emb = (fp32p)d_in[I[11]];
  fp32p wpost= (fp32p)d_in[I[12]], bpost= (fp32p)d_in[I[13]];
  fp32p wd1  = (fp32p)d_in[I[14]], bd1 = (fp32p)d_in[I[15]], g3 = (fp32p)d_in[I[16]], be3 = (fp32p)d_in[I[17]];
  fp32p wd2  = (fp32p)d_in[I[18]], bd2 = (fp32p)d_in[I[19]];

  char* wsb = (char*)d_ws;
  float* h1   = (float*)(wsb);                    // f32, reused as h3
  float* h2   = (float*)(wsb + 67108864);
  float* di   = (float*)(wsb + 71303168);
  double* bn  = (double*)(wsb + 75497472);        // 128 doubles
  double* redE = bn + 128;                        // 256 doubles
  double* redH = bn + 384;                        // 4096 doubles
  float* out = (float*)d_out;

  k_init    <<<1,128,0,stream>>>(bn);
  k_conv1   <<<4096,256,0,stream>>>(x, w1, b1, h1);
  k_statsd<16><<<512,256,0,stream>>>(h1, 4194304, bn);         // bn1
  k_conv2   <<<1024,256,0,stream>>>(h1, w2, b2, g1, be1, bn, h2);
  k_statsd<4><<<256,256,0,stream>>>(h2, 262144, bn+32);        // bn2
  k_vq      <<<256,256,0,stream>>>(h2, g2, be2, bn, wpre, bpre, emb, wpost, bpost, di, redE);
  k_convt1  <<<4096,256,0,stream>>>(di, wd1, bd1, h1);         // h3 reuses h1
  k_statsd<16><<<512,256,0,stream>>>(h1, 4194304, bn+40);      // bn3
  k_convt2  <<<4096,256,0,stream>>>(h1, wd2, bd2, g3, be3, bn, x, out, redH);
  k_final   <<<1,256,0,stream>>>(redE, redH, out, out_size);
}

// Round 4
// 256.869 us; speedup vs baseline: 1.0210x; 1.0210x over previous
//
#include <hip/hip_runtime.h>
#include <hip/hip_bf16.h>

typedef const float* fp32p;

// ---------------- workspace layout (bytes) ----------------
// h1: 64*128*128*16 f32 = 67,108,864 B                  @ 0
// h2: 64*64*64*4 f32 = 4,194,304 B                      @ 67,108,864
// di: 64*64*64*4 f32 = 4,194,304 B                      @ 71,303,168
// bnf float[64]: sc1[0:16) sh1[16:32) sc3[32:48) sh3[48:64)   @ 75,497,472
// bnd double[8]: sc2d[0:4) sh2d[4:8)                    @ 75,497,728
// redE double[256]                                      @ 75,498,496
// redH double[4096]                                     @ 75,500,544
// partial1 float[32*4096] aliases h2 region (dead then) @ 67,108,864
// partial2 float[8*1024]  aliases di region (dead then) @ 71,303,168
// partial3 float[32*4096] aliases h1 region (dead then) @ 0
// max ws use = 75,533,312 B (same as round 3)

__device__ __forceinline__ double block_sum_all_d(double v, double* sm){
  #pragma unroll
  for (int m=1;m<64;m<<=1) v += __shfl_xor(v, m, 64);
  int lane = threadIdx.x & 63, wid = threadIdx.x >> 6;
  if (lane==0) sm[wid] = v;
  __syncthreads();
  return sm[0]+sm[1]+sm[2]+sm[3];
}

template<int NV>
__device__ __forceinline__ void wave_reduce(float* a){
  #pragma unroll
  for (int m=1;m<64;m<<=1){
    #pragma unroll
    for (int k=0;k<NV;k++) a[k] += __shfl_xor(a[k], m, 64);
  }
}

// ---------------- K1: conv1 1->16 k4 s2 p1 + fused per-block stats partials
__global__ __launch_bounds__(256) void k_conv1(fp32p x, fp32p w1, fp32p b1,
                                               float* __restrict__ h1, float* __restrict__ part){
  __shared__ float sw[256];   // [ky][kx][co]
  __shared__ float sb[16];
  __shared__ float red[4][32];
  int tid = threadIdx.x;
  {
    int co = tid & 15, kx = (tid>>4)&3, ky = tid>>6;
    sw[tid] = w1[co*16 + ky*4 + kx];
    if (tid < 16) sb[tid] = b1[tid];
  }
  __syncthreads();
  int gid = blockIdx.x*256 + tid;           // 64*128*128 threads
  int ox = gid & 127, oy = (gid>>7)&127, n = gid>>14;
  float acc[16];
  #pragma unroll
  for (int c=0;c<16;c++) acc[c] = sb[c];
  #pragma unroll
  for (int ky=0; ky<4; ky++){
    int iy = oy*2 - 1 + ky;
    bool rok = (unsigned)iy < 256u;
    #pragma unroll
    for (int kx=0; kx<4; kx++){
      int ix = ox*2 - 1 + kx;
      float v = (rok && ((unsigned)ix < 256u)) ? x[n*65536 + iy*256 + ix] : 0.f;
      const float* wp = &sw[(ky*4+kx)*16];
      #pragma unroll
      for (int c=0;c<16;c++) acc[c] = fmaf(v, wp[c], acc[c]);
    }
  }
  float* o = &h1[(unsigned)gid*16u];
  #pragma unroll
  for (int q=0;q<4;q++)
    *(float4*)&o[q*4] = make_float4(acc[q*4],acc[q*4+1],acc[q*4+2],acc[q*4+3]);
  // stats partials
  float st[32];
  #pragma unroll
  for (int c=0;c<16;c++){ st[c]=acc[c]; st[16+c]=acc[c]*acc[c]; }
  wave_reduce<32>(st);
  int lane = tid & 63, wid = tid >> 6;
  if (lane==0){
    #pragma unroll
    for (int k=0;k<32;k++) red[wid][k]=st[k];
  }
  __syncthreads();
  if (tid<32){
    float v = red[0][tid]+red[1][tid]+red[2][tid]+red[3][tid];
    part[tid*4096 + blockIdx.x] = v;
  }
}

// ---------------- reduce partials -> float scale/shift
__global__ __launch_bounds__(256) void k_redf(const float* __restrict__ part, int N, int nch,
    fp32p g, fp32p be, double cnt, float* __restrict__ sc, float* __restrict__ sh){
  __shared__ double sm[4];
  int c = blockIdx.x;
  double s=0.0, q=0.0;
  for (int i=threadIdx.x;i<N;i+=256){ s += (double)part[c*N+i]; q += (double)part[(nch+c)*N+i]; }
  s = block_sum_all_d(s, sm); __syncthreads();
  q = block_sum_all_d(q, sm);
  if (threadIdx.x==0){
    double m = s/cnt;
    double var = q/cnt - m*m;
    double sd = (double)g[c] / sqrt(var + 1e-5);
    sc[c] = (float)sd;
    sh[c] = (float)((double)be[c] - m*sd);
  }
}

// ---------------- reduce partials -> double scale/shift (BN2, argmin-critical)
__global__ __launch_bounds__(256) void k_redd(const float* __restrict__ part, int N, int nch,
    fp32p g, fp32p be, double cnt, double* __restrict__ sc, double* __restrict__ sh){
  __shared__ double sm[4];
  int c = blockIdx.x;
  double s=0.0, q=0.0;
  for (int i=threadIdx.x;i<N;i+=256){ s += (double)part[c*N+i]; q += (double)part[(nch+c)*N+i]; }
  s = block_sum_all_d(s, sm); __syncthreads();
  q = block_sum_all_d(q, sm);
  if (threadIdx.x==0){
    double m = s/cnt;
    double var = q/cnt - m*m;
    double sd = (double)g[c] / sqrt(var + 1e-5);
    sc[c] = sd;
    sh[c] = (double)be[c] - m*sd;
  }
}

// ---------------- K2: BN1+ReLU fused read, conv2 16->4 k4 s2 p1 + stats partials
__global__ __launch_bounds__(256) void k_conv2(const float* __restrict__ h1, fp32p w2, fp32p b2,
    const float* __restrict__ sc1, const float* __restrict__ sh1,
    float* __restrict__ h2, float* __restrict__ part){
  __shared__ float sw[1024];   // [ky][kx][ci16][co4]
  __shared__ float sb[4];
  __shared__ float red[4][8];
  int tid = threadIdx.x;
  for (int j=tid;j<1024;j+=256){
    int co=j&3, ci=(j>>2)&15, kx=(j>>6)&3, ky=j>>8;
    sw[j] = w2[((co*16+ci)*4+ky)*4+kx];
  }
  if (tid<4) sb[tid]=b2[tid];
  __syncthreads();
  float sc[16], sh[16];
  #pragma unroll
  for (int c=0;c<16;c++){ sc[c]=sc1[c]; sh[c]=sh1[c]; }
  int gid = blockIdx.x*256+tid;             // 64*64*64 threads
  int ox = gid&63, oy=(gid>>6)&63, n=gid>>12;
  float a0=sb[0],a1=sb[1],a2=sb[2],a3=sb[3];
  #pragma unroll
  for (int ky=0;ky<4;ky++){
    int iy = oy*2-1+ky;
    if ((unsigned)iy >= 128u) continue;
    #pragma unroll
    for (int kx=0;kx<4;kx++){
      int ix = ox*2-1+kx;
      if ((unsigned)ix >= 128u) continue;
      const float4* hp = (const float4*)&h1[((n*128+iy)*128+ix)*16];
      const float* wp = &sw[(ky*4+kx)*64];
      #pragma unroll
      for (int c4=0;c4<4;c4++){
        float4 hv = hp[c4];
        float vv[4]={hv.x,hv.y,hv.z,hv.w};
        #pragma unroll
        for (int u=0;u<4;u++){
          int ci=c4*4+u;
          float v = fmaxf(fmaf(vv[u], sc[ci], sh[ci]), 0.f);
          const float* w4 = &wp[ci*4];
          a0 = fmaf(v,w4[0],a0); a1 = fmaf(v,w4[1],a1);
          a2 = fmaf(v,w4[2],a2); a3 = fmaf(v,w4[3],a3);
        }
      }
    }
  }
  *(float4*)&h2[(unsigned)gid*4u] = make_float4(a0,a1,a2,a3);
  float st[8] = {a0,a1,a2,a3, a0*a0,a1*a1,a2*a2,a3*a3};
  wave_reduce<8>(st);
  int lane = tid & 63, wid = tid >> 6;
  if (lane==0){
    #pragma unroll
    for (int k=0;k<8;k++) red[wid][k]=st[k];
  }
  __syncthreads();
  if (tid<8){
    float v = red[0][tid]+red[1][tid]+red[2][tid]+red[3][tid];
    part[tid*1024 + blockIdx.x] = v;
  }
}

// ---------------- K3: BN2(d)+ReLU -> pre 1x1 -> VQ argmin (fp64) -> loss -> post 1x1 -> di
__global__ __launch_bounds__(256) void k_vq(const float* __restrict__ h2,
    const double* __restrict__ bnd,
    fp32p wpre, fp32p bpre, fp32p emb, fp32p wpost, fp32p bpost,
    float* __restrict__ di, double* __restrict__ redE){
  __shared__ double se[128];
  __shared__ double sm[4];
  int tid = threadIdx.x;
  if (tid < 128) se[tid] = (double)emb[tid];
  __syncthreads();
  double sc[4], sh[4];
  #pragma unroll
  for (int c=0;c<4;c++){ sc[c]=bnd[c]; sh[c]=bnd[4+c]; }
  double wa0=wpre[0], wa1=wpre[1], wa2=wpre[2], wa3=wpre[3];
  double wb0=wpre[4], wb1=wpre[5], wb2=wpre[6], wb3=wpre[7];
  double bp0=bpre[0], bp1=bpre[1];
  double p00=wpost[0], p01=wpost[1];
  double p10=wpost[2], p11=wpost[3];
  double p20=wpost[4], p21=wpost[5];
  double p30=wpost[6], p31=wpost[7];
  double bq0=bpost[0], bq1=bpost[1], bq2=bpost[2], bq3=bpost[3];
  int gid = blockIdx.x*256 + tid;           // 65536 threads, 4 pixels each
  double lsum = 0.0;
  #pragma unroll
  for (int it=0; it<4; it++){
    int p = gid + it*65536;
    float4 hv = *(const float4*)&h2[(unsigned)p*4u];
    double h0 = fmax(fma((double)hv.x, sc[0], sh[0]), 0.0);
    double h1v = fmax(fma((double)hv.y, sc[1], sh[1]), 0.0);
    double h2v = fmax(fma((double)hv.z, sc[2], sh[2]), 0.0);
    double h3v = fmax(fma((double)hv.w, sc[3], sh[3]), 0.0);
    double z0 = bp0 + wa0*h0 + wa1*h1v + wa2*h2v + wa3*h3v;
    double z1 = bp1 + wb0*h0 + wb1*h1v + wb2*h2v + wb3*h3v;
    double best = 1e300; int bi = 0;
    #pragma unroll
    for (int k=0;k<64;k++){
      double d0 = z0 - se[2*k], d1 = z1 - se[2*k+1];
      double d = fma(d0,d0, d1*d1);
      if (d < best){ best = d; bi = k; }    // first-min tie rule == argmin
    }
    double qv0 = se[2*bi], qv1 = se[2*bi+1];
    double e0 = qv0-z0, e1 = qv1-z1;
    lsum += fma(e0,e0, e1*e1);
    float4 o;
    o.x = (float)(fma(p00,qv0, fma(p01,qv1, bq0)));
    o.y = (float)(fma(p10,qv0, fma(p11,qv1, bq1)));
    o.z = (float)(fma(p20,qv0, fma(p21,qv1, bq2)));
    o.w = (float)(fma(p30,qv0, fma(p31,qv1, bq3)));
    *(float4*)&di[(unsigned)p*4u] = o;
  }
  double tot = block_sum_all_d(lsum, sm);
  if (tid==0) redE[blockIdx.x] = tot;
}

// ---------------- K4: BN3 stats via convT1 recompute (no h3 store)
__global__ __launch_bounds__(256) void k_stats3(const float* __restrict__ di, fp32p wd1, fp32p bd1,
                                                float* __restrict__ part){
  __shared__ float sw[1024];  // [ky][kx][ci4][co16]
  __shared__ float sb[16];
  __shared__ float red[4][32];
  int tid = threadIdx.x;
  for (int j=tid; j<1024; j+=256){
    int co = j & 15, ci = (j>>4)&3, kx = (j>>6)&3, ky = j>>8;
    sw[j] = wd1[((ci*16+co)*4+ky)*4+kx];   // wd1 [in4][out16][4][4]
  }
  if (tid<16) sb[tid] = bd1[tid];
  __syncthreads();
  int gid = blockIdx.x*256 + tid;          // 64*128*128 threads (one h3 px each)
  int ox = gid & 127, oy = (gid>>7)&127, n = gid>>14;
  float acc[16];
  #pragma unroll
  for (int c=0;c<16;c++) acc[c]=sb[c];
  int py=(oy+1)&1, px=(ox+1)&1;
  #pragma unroll
  for (int j=0;j<2;j++){
    int ky = py + 2*j;
    int iy = (oy+1-ky) >> 1;
    if ((unsigned)iy >= 64u) continue;
    #pragma unroll
    for (int i=0;i<2;i++){
      int kx = px + 2*i;
      int ix = (ox+1-kx) >> 1;
      if ((unsigned)ix >= 64u) continue;
      float4 dv = *(const float4*)&di[((n*64+iy)*64+ix)*4];
      const float* wb = &sw[((ky*4+kx)*4)*16];
      float vv[4] = {dv.x, dv.y, dv.z, dv.w};
      #pragma unroll
      for (int ci=0;ci<4;ci++){
        #pragma unroll
        for (int co=0;co<16;co++)
          acc[co] = fmaf(vv[ci], wb[ci*16+co], acc[co]);
      }
    }
  }
  float st[32];
  #pragma unroll
  for (int c=0;c<16;c++){ st[c]=acc[c]; st[16+c]=acc[c]*acc[c]; }
  wave_reduce<32>(st);
  int lane = tid & 63, wid = tid >> 6;
  if (lane==0){
    #pragma unroll
    for (int k=0;k<32;k++) red[wid][k]=st[k];
  }
  __syncthreads();
  if (tid<32){
    float v = red[0][tid]+red[1][tid]+red[2][tid]+red[3][tid];
    part[tid*4096 + blockIdx.x] = v;
  }
}

// ---------------- K5: fused convT1 -> BN3+ReLU (LDS) -> convT2 -> tanh -> out + recon loss
// One block = 32x32 output tile. h3 tile 18x18x16 lives in LDS as [q][18][19][4].
__global__ __launch_bounds__(256) void k_fuseT(const float* __restrict__ di,
    fp32p wd1, fp32p bd1, fp32p wd2, fp32p bd2,
    const float* __restrict__ sc3, const float* __restrict__ sh3,
    fp32p x, float* __restrict__ out, double* __restrict__ redH){
  __shared__ float swt[1024];  // convT1 weights [ky][kx][ci4][co16]
  __shared__ float sb1[16];
  __shared__ float sw2[256];   // convT2 weights [ky][kx][ci16]
  __shared__ float h3q[4][18][19][4];
  __shared__ double smd[4];
  int tid = threadIdx.x;
  for (int j=tid; j<1024; j+=256){
    int co = j & 15, ci = (j>>4)&3, kx = (j>>6)&3, ky = j>>8;
    swt[j] = wd1[((ci*16+co)*4+ky)*4+kx];
  }
  { int ci = tid & 15, kx = (tid>>4)&3, ky = tid>>6;
    sw2[tid] = wd2[ci*16 + ky*4 + kx]; }
  if (tid<16) sb1[tid] = bd1[tid];
  float s3[16], h3s[16];
  #pragma unroll
  for (int c=0;c<16;c++){ s3[c]=sc3[c]; h3s[c]=sh3[c]; }
  int b = blockIdx.x;
  int n = b>>6, ty=(b>>3)&7, tx=b&7;
  int OY=ty*32, OX=tx*32;
  int R0=ty*16-1, C0=tx*16-1;
  __syncthreads();
  // Phase A: compute 18x18 h3 tile, BN3+ReLU, store to LDS
  for (int p=tid; p<324; p+=256){
    int rr = p/18, cc = p - rr*18;
    int r = R0+rr, c = C0+cc;
    float v[16];
    if ((unsigned)r < 128u && (unsigned)c < 128u){
      float acc[16];
      #pragma unroll
      for (int ch=0;ch<16;ch++) acc[ch]=sb1[ch];
      int py=(r+1)&1, pxx=(c+1)&1;
      #pragma unroll
      for (int j=0;j<2;j++){
        int ky = py + 2*j;
        int iy = (r+1-ky) >> 1;
        if ((unsigned)iy >= 64u) continue;
        #pragma unroll
        for (int i=0;i<2;i++){
          int kx = pxx + 2*i;
          int ix = (c+1-kx) >> 1;
          if ((unsigned)ix >= 64u) continue;
          float4 dv = *(const float4*)&di[((n*64+iy)*64+ix)*4];
          const float* wb = &swt[((ky*4+kx)*4)*16];
          float vv[4] = {dv.x, dv.y, dv.z, dv.w};
          #pragma unroll
          for (int ci=0;ci<4;ci++){
            #pragma unroll
            for (int co=0;co<16;co++)
              acc[co] = fmaf(vv[ci], wb[ci*16+co], acc[co]);
          }
        }
      }
      #pragma unroll
      for (int ch=0;ch<16;ch++) v[ch] = fmaxf(fmaf(acc[ch], s3[ch], h3s[ch]), 0.f);
    } else {
      #pragma unroll
      for (int ch=0;ch<16;ch++) v[ch]=0.f;
    }
    #pragma unroll
    for (int q=0;q<4;q++)
      *(float4*)&h3q[q][rr][cc][0] = make_float4(v[4*q],v[4*q+1],v[4*q+2],v[4*q+3]);
  }
  __syncthreads();
  // Phase B: convT2 from LDS, 4 output px per thread (1 row x 4 cols)
  int row = tid>>3, tc = tid&7;
  int oy = OY + row, ox0 = OX + tc*4;
  float bias = bd2[0];
  int base = (n*256+oy)*256 + ox0;
  float4 xv = *(const float4*)&x[base];
  float r4[4];
  double rsum = 0.0;
  #pragma unroll
  for (int k=0;k<4;k++){
    int ox = ox0 + k;
    int py = (oy+1)&1, pxx = (ox+1)&1;
    float acc = bias;
    #pragma unroll
    for (int j=0;j<2;j++){
      int ky = py + 2*j;
      int iy = (oy + 1 - ky) >> 1;
      int rr = iy - R0;                 // always in [0,17]
      #pragma unroll
      for (int i=0;i<2;i++){
        int kx = pxx + 2*i;
        int ix = (ox + 1 - kx) >> 1;
        int cc = ix - C0;               // always in [0,17]
        const float* w16 = &sw2[(ky*4+kx)*16];
        #pragma unroll
        for (int q=0;q<4;q++){
          float4 hv = *(const float4*)&h3q[q][rr][cc][0];
          acc = fmaf(hv.x, w16[4*q+0], acc);
          acc = fmaf(hv.y, w16[4*q+1], acc);
          acc = fmaf(hv.z, w16[4*q+2], acc);
          acc = fmaf(hv.w, w16[4*q+3], acc);
        }
      }
    }
    float e = __expf(2.f*acc);
    float t = 1.f - 2.f/(e+1.f);        // tanh
    r4[k] = t;
    float xd = (k==0?xv.x:k==1?xv.y:k==2?xv.z:xv.w);
    double dd = (double)xd - (double)t;
    rsum = fma(dd,dd,rsum);
  }
  *(float4*)&out[base] = make_float4(r4[0],r4[1],r4[2],r4[3]);
  double tot = block_sum_all_d(rsum, smd);
  if (tid==0) redH[b] = tot;
}

// ---------------- K6: finalize loss
__global__ __launch_bounds__(256) void k_final(const double* __restrict__ redE, const double* __restrict__ redH,
                                               float* __restrict__ out, int out_size){
  __shared__ double sm[4];
  int tid = threadIdx.x;
  double a = redE[tid];        // exactly 256 entries
  double b = 0.0;
  for (int i=tid;i<4096;i+=256) b += redH[i];
  double ta = block_sum_all_d(a, sm);
  __syncthreads();
  double tb = block_sum_all_d(b, sm);
  if (tid==0){
    double loss = 1.2*ta/524288.0 + tb/4194304.0;  // (1+BETA)*mean((q-z)^2) + recon_mean
    out[out_size-1] = (float)loss;
  }
}

extern "C" void kernel_launch(void* const* d_in, const int* in_sizes, int n_in,
                              void* d_out, int out_size, void* d_ws, size_t ws_size,
                              hipStream_t stream) {
  (void)ws_size;
  int I[20];
  for (int i=0;i<20;i++) I[i]=i;
  if (n_in >= 20 && in_sizes[0] != 4194304 && in_sizes[19] == 4194304){
    static const int remap[20] = {19,13,0,10,4,14,1,11,5,18,8,9,17,7,15,2,12,6,16,3};
    for (int i=0;i<20;i++) I[i]=remap[i];
  }
  fp32p x    = (fp32p)d_in[I[0]];
  fp32p w1   = (fp32p)d_in[I[1]],  b1 = (fp32p)d_in[I[2]],  g1 = (fp32p)d_in[I[3]],  be1 = (fp32p)d_in[I[4]];
  fp32p w2   = (fp32p)d_in[I[5]],  b2 = (fp32p)d_in[I[6]],  g2 = (fp32p)d_in[I[7]],  be2 = (fp32p)d_in[I[8]];
  fp32p wpre = (fp32p)d_in[I[9]],  bpre = (fp32p)d_in[I[10]], emb = (fp32p)d_in[I[11]];
  fp32p wpost= (fp32p)d_in[I[12]], bpost= (fp32p)d_in[I[13]];
  fp32p wd1  = (fp32p)d_in[I[14]], bd1 = (fp32p)d_in[I[15]], g3 = (fp32p)d_in[I[16]], be3 = (fp32p)d_in[I[17]];
  fp32p wd2  = (fp32p)d_in[I[18]], bd2 = (fp32p)d_in[I[19]];

  char* wsb = (char*)d_ws;
  float* h1    = (float*)(wsb);                    // f32
  float* h2    = (float*)(wsb + 67108864);
  float* di    = (float*)(wsb + 71303168);
  float* bnf   = (float*)(wsb + 75497472);         // sc1,sh1,sc3,sh3
  double* bnd  = (double*)(wsb + 75497728);        // sc2d[4], sh2d[4]
  double* redE = (double*)(wsb + 75498496);        // 256
  double* redH = (double*)(wsb + 75500544);        // 4096
  float* part1 = (float*)(wsb + 67108864);         // aliases h2 (consumed before K2 writes h2)
  float* part2 = (float*)(wsb + 71303168);         // aliases di (consumed before K3 writes di)
  float* part3 = (float*)(wsb);                    // aliases h1 (h1 dead after K2)
  float* sc1 = bnf, *sh1 = bnf+16, *sc3 = bnf+32, *sh3 = bnf+48;
  float* out = (float*)d_out;

  k_conv1 <<<4096,256,0,stream>>>(x, w1, b1, h1, part1);
  k_redf  <<<16,256,0,stream>>>(part1, 4096, 16, g1, be1, 1048576.0, sc1, sh1);
  k_conv2 <<<1024,256,0,stream>>>(h1, w2, b2, sc1, sh1, h2, part2);
  k_redd  <<<4,256,0,stream>>>(part2, 1024, 4, g2, be2, 262144.0, bnd, bnd+4);
  k_vq    <<<256,256,0,stream>>>(h2, bnd, wpre, bpre, emb, wpost, bpost, di, redE);
  k_stats3<<<4096,256,0,stream>>>(di, wd1, bd1, part3);
  k_redf  <<<16,256,0,stream>>>(part3, 4096, 16, g3, be3, 1048576.0, sc3, sh3);
  k_fuseT <<<4096,256,0,stream>>>(di, wd1, bd1, wd2, bd2, sc3, sh3, x, out, redH);
  k_final <<<1,256,0,stream>>>(redE, redH, out, out_size);
}